// Round 15
// baseline (60.762 us; speedup 1.0000x reference)
//
#include <hip/hip_runtime.h>
#include <hip/hip_bf16.h>
#include <stdint.h>

// Recommender: B=4096 users, L=200 history, D=64 emb, F=100000 films.
// Kernel A (stats): ONE USER PER WAVE, lane = dim; 4 independent waves per
//   256-thread block (1024 blocks), ZERO LDS, zero barriers.
//   __launch_bounds__(256, 1): min 1 wave/EU -> VGPR cap 512, so the ~175-reg
//   live set (112 plane regs + ping-pong ev buffers) stays IN REGISTERS.
//   (Rounds 10-14 all silently spilled the planes to scratch at VGPR<=108 --
//   that spill, not the gather schedule, was the flat 41us plateau.)
//   GATHER IS SOFTWARE-PIPELINED (ping-pong evA/evB, 16 rows per half-chunk):
//   next half-chunk's 16 independent loads issue BEFORE current is consumed.
//   Row bases via v_readlane of register-held byte offsets; weights readlane'd
//   at consume. Keys: raw high-16 halves packed 2/word (v_perm), per-32-key
//   chunk dual 16x16 bit-transpose (verified), sortable-sign fix in plane
//   space (S = sign plane: plane15 = ~S, plane_b ^= S). Bit-serial popc
//   median select templated on nct = ceil(n/32) (verified, absmax 0).
// Kernel B: tiny MLP 320->128->64->1 + sigmoid, 4 users/block (unchanged).

#define B_ 4096
#define L_ 200
#define D_ 64

template<int NC>
__device__ __forceinline__ uint32_t select_kth(
    const uint32_t (&PL)[7][16], const uint32_t (&alive0)[7], int k)
{
  uint32_t alive[NC];
  int na = 0;
  #pragma unroll
  for (int c = 0; c < NC; ++c) { alive[c] = alive0[c]; na += __popc(alive[c]); }
  uint32_t prefix = 0;
  #pragma unroll
  for (int bb = 15; bb >= 0; --bb) {
    uint32_t t1[NC]; int cnt1 = 0;
    #pragma unroll
    for (int c = 0; c < NC; ++c) {
      t1[c] = alive[c] & PL[c][15 - bb];
      cnt1 += __popc(t1[c]);
    }
    const int cnt0 = na - cnt1;
    const bool zs = (k < cnt0);
    #pragma unroll
    for (int c = 0; c < NC; ++c) alive[c] = zs ? (alive[c] ^ t1[c]) : t1[c];
    na = zs ? cnt0 : cnt1;
    k  = zs ? k : (k - cnt0);
    prefix = zs ? prefix : (prefix | (1u << bb));
  }
  return prefix;
}

__global__ __launch_bounds__(256, 1) void stats_kernel(
    const int* __restrict__ film_hist,
    const float* __restrict__ ratings,
    const int* __restrict__ lengths,
    const int* __restrict__ film_indices,
    const float* __restrict__ emb,
    float* __restrict__ x)
{
  const int t = threadIdx.x;
  const int wv = t >> 6;
  const int lane = t & 63;
  const int b = blockIdx.x * 4 + wv;
  const int n = lengths[b];                  // wave-uniform

  // film embedding (issue early; fully coalesced)
  const int fi = film_indices[b];
  const float fev = emb[(size_t)fi * D_ + lane];

  const int*   hp = film_hist + (size_t)b * L_;
  const float* rp = ratings  + (size_t)b * L_;

  // ---- coalesced history/ratings load into registers + mean rating ----
  uint32_t ov[4];                            // per-row emb BYTE offsets
  float    wtv[4];                           // per-row weights (rat - mean + .1)
  float rsum = 0.f;
  #pragma unroll
  for (int j = 0; j < 4; ++j) {
    const int l = lane + 64*j;
    const bool v = l < n;
    const int h = v ? hp[l] : 0;
    const float r = v ? rp[l] : 0.f;
    ov[j] = ((uint32_t)h) << 8;              // h * 256 bytes per row
    wtv[j] = r;
    rsum += r;
  }
  #pragma unroll
  for (int off = 32; off; off >>= 1) rsum += __shfl_xor(rsum, off);
  const float mr1 = 0.1f - rsum / (float)n;
  #pragma unroll
  for (int j = 0; j < 4; ++j) wtv[j] += mr1;

  const char* eb = (const char*)emb;
  const uint32_t lane4 = (uint32_t)lane * 4u;

  // issue 16 loads of half-chunk HC into BUF (rows >= n read row 0; masked later)
  #define LOADH(HC, BUF) { \
    _Pragma("unroll") \
    for (int i = 0; i < 16; ++i) { \
      const int r_ = 16*(HC) + i; \
      const uint32_t off_ = __builtin_amdgcn_readlane(ov[r_>>6], r_&63); \
      BUF[i] = *(const float*)(eb + off_ + lane4); \
    } }

  // consume half-chunk HC from BUF -> 8 packed key words at WDST
  #define CONS(HC, BUF, WDST, FULL) { \
    _Pragma("unroll") \
    for (int p = 0; p < 8; ++p) { \
      const int i0_ = 16*(HC) + 2*p, i1_ = i0_ + 1; \
      const float wt0_ = __uint_as_float( \
          __builtin_amdgcn_readlane(__float_as_uint(wtv[i0_>>6]), i0_&63)); \
      const float wt1_ = __uint_as_float( \
          __builtin_amdgcn_readlane(__float_as_uint(wtv[i1_>>6]), i1_&63)); \
      const float w0_ = BUF[2*p]   * wt0_; \
      const float w1_ = BUF[2*p+1] * wt1_; \
      if (FULL) { \
        vmin = fminf(fminf(vmin, w0_), w1_); \
        vmax = fmaxf(fmaxf(vmax, w0_), w1_); \
        vsum += w0_ + w1_; \
      } else { \
        vmin = fminf(vmin, (i0_ < n) ? w0_ :  __builtin_inff()); \
        vmin = fminf(vmin, (i1_ < n) ? w1_ :  __builtin_inff()); \
        vmax = fmaxf(vmax, (i0_ < n) ? w0_ : -__builtin_inff()); \
        vmax = fmaxf(vmax, (i1_ < n) ? w1_ : -__builtin_inff()); \
        vsum += (i0_ < n) ? w0_ : 0.f; \
        vsum += (i1_ < n) ? w1_ : 0.f; \
      } \
      (WDST)[p] = __builtin_amdgcn_perm(__float_as_uint(w1_), \
                                        __float_as_uint(w0_), 0x07060302u); \
    } }

  // ---- pipelined gather + stats + raw bit-plane build: 7 chunks of 32 ----
  float vmin = __builtin_inff(), vmax = -__builtin_inff(), vsum = 0.f;
  uint32_t PL[7][16];
  float evA[16], evB[16];

  LOADH(0, evA);                             // prologue: first half-chunk
  #pragma unroll
  for (int c = 0; c < 7; ++c) {
    uint32_t* Wc = PL[c];
    if (n > 32*c) {                          // wave-uniform guard
      const bool full = (32*c + 32 <= n);    // wave-uniform
      LOADH(2*c+1, evB);                     // in flight during consume(A)
      CONS(2*c, evA, Wc, full);
      if (n > 32*(c+1)) LOADH(2*c+2, evA);   // in flight during consume(B)+transpose
      CONS(2*c+1, evB, Wc+8, full);
      // dual 16x16 bit-matrix transpose (verified network) of RAW halves:
      // Wc[j] = plane of raw key-bit (15-j); key i at bit (15-(i>>1))+16*(i&1)
      #define XS(k, jj, m) { uint32_t tt = ((Wc[k] ^ (Wc[(k)|(jj)] >> (jj))) & (m)); \
                             Wc[k] ^= tt; Wc[(k)|(jj)] ^= (tt << (jj)); }
      XS(0,8,0x00FF00FFu) XS(1,8,0x00FF00FFu) XS(2,8,0x00FF00FFu) XS(3,8,0x00FF00FFu)
      XS(4,8,0x00FF00FFu) XS(5,8,0x00FF00FFu) XS(6,8,0x00FF00FFu) XS(7,8,0x00FF00FFu)
      XS(0,4,0x0F0F0F0Fu) XS(1,4,0x0F0F0F0Fu) XS(2,4,0x0F0F0F0Fu) XS(3,4,0x0F0F0F0Fu)
      XS(8,4,0x0F0F0F0Fu) XS(9,4,0x0F0F0F0Fu) XS(10,4,0x0F0F0F0Fu) XS(11,4,0x0F0F0F0Fu)
      XS(0,2,0x33333333u) XS(1,2,0x33333333u) XS(4,2,0x33333333u) XS(5,2,0x33333333u)
      XS(8,2,0x33333333u) XS(9,2,0x33333333u) XS(12,2,0x33333333u) XS(13,2,0x33333333u)
      XS(0,1,0x55555555u) XS(2,1,0x55555555u) XS(4,1,0x55555555u) XS(6,1,0x55555555u)
      XS(8,1,0x55555555u) XS(10,1,0x55555555u) XS(12,1,0x55555555u) XS(14,1,0x55555555u)
      #undef XS
      // sortable-key transform in plane space: key15 = ~sign; key_b = raw_b ^ sign
      {
        const uint32_t S = Wc[0];            // raw bit15 (sign) plane
        Wc[0] = ~S;
        #pragma unroll
        for (int j = 1; j < 16; ++j) Wc[j] ^= S;
      }
    } else {
      #pragma unroll
      for (int j = 0; j < 16; ++j) Wc[j] = 0u;
    }
  }
  #undef LOADH
  #undef CONS

  // ---- alive masks (verified formula, per chunk) ----
  uint32_t alive[7];
  #pragma unroll
  for (int c = 0; c < 7; ++c) {
    int v = n - 32*c; v = (v < 0) ? 0 : (v > 32 ? 32 : v);
    const int ce = (v + 1) >> 1, cf = v >> 1;
    uint32_t a = ((1u << ce) - 1u) << (16 - ce);
    if (cf) a |= ((1u << cf) - 1u) << (32 - cf);
    alive[c] = a;
  }

  // ---- bit-serial select, templated on active chunk count ----
  const int k = (n - 1) >> 1;
  const int nct = (n + 31) >> 5;             // wave-uniform
  uint32_t prefix;
  switch (nct) {
    case 1: prefix = select_kth<1>(PL, alive, k); break;
    case 2: prefix = select_kth<2>(PL, alive, k); break;
    case 3: prefix = select_kth<3>(PL, alive, k); break;
    case 4: prefix = select_kth<4>(PL, alive, k); break;
    case 5: prefix = select_kth<5>(PL, alive, k); break;
    case 6: prefix = select_kth<6>(PL, alive, k); break;
    default: prefix = select_kth<7>(PL, alive, k); break;
  }

  uint32_t key32 = (prefix << 16) | 0x8000u;           // bucket midpoint
  const float med = (prefix & 0x8000u) ? __uint_as_float(key32 ^ 0x80000000u)
                                       : __uint_as_float(~key32);
  const float mean = vsum / (float)n;

  // ---- L2-normalize (wave reduce of 4-term sumsq) and write x ----
  float ss = vmin*vmin + vmax*vmax + mean*mean + med*med;
  #pragma unroll
  for (int off = 32; off; off >>= 1) ss += __shfl_xor(ss, off);
  const float rn = 1.0f / sqrtf(ss);

  float* xb = x + (size_t)b * 320;
  xb[lane]        = vmin * rn;
  xb[64  + lane]  = vmax * rn;
  xb[128 + lane]  = mean * rn;
  xb[192 + lane]  = med  * rn;
  xb[256 + lane]  = fev;
}

#define U_ 4   // users per MLP block -> 1024 blocks

__global__ __launch_bounds__(256) void mlp_kernel(
    const float* __restrict__ x,
    const float* __restrict__ W1, const float* __restrict__ b1,
    const float* __restrict__ W2, const float* __restrict__ b2,
    const float* __restrict__ W3, const float* __restrict__ b3,
    float* __restrict__ out)
{
  __shared__ float xs[U_*320];
  __shared__ float h1s[U_*128];
  __shared__ float h2s[U_*64];
  const int t = threadIdx.x;
  const int u0 = blockIdx.x * U_;

  for (int i = t; i < U_*80; i += 256)
    ((float4*)xs)[i] = ((const float4*)(x + (size_t)u0*320))[i];
  __syncthreads();

  // h1 = relu(x @ W1 + b1): 4 users x 128 out; thread = (j, 2-user group)
  {
    const int j = t & 127, g = t >> 7;
    const int ub = g*2;
    float acc[2];
    const float bj = b1[j];
    acc[0] = bj; acc[1] = bj;
    for (int i = 0; i < 320; i += 4) {
      float w0 = W1[(i+0)*128 + j];
      float w1 = W1[(i+1)*128 + j];
      float w2 = W1[(i+2)*128 + j];
      float w3 = W1[(i+3)*128 + j];
      #pragma unroll
      for (int q = 0; q < 2; ++q) {
        float4 xv = *(const float4*)&xs[(ub+q)*320 + i];   // LDS broadcast in-wave
        acc[q] += xv.x*w0 + xv.y*w1 + xv.z*w2 + xv.w*w3;
      }
    }
    #pragma unroll
    for (int q = 0; q < 2; ++q) h1s[(ub+q)*128 + j] = fmaxf(acc[q], 0.f);
  }
  __syncthreads();

  // h2 = relu(h1 @ W2 + b2): 4 users x 64 out, 1 user per 64-thread group
  {
    const int j = t & 63, g = t >> 6;
    float acc = b2[j];
    for (int i = 0; i < 128; i += 4) {
      float w0 = W2[(i+0)*64 + j];
      float w1 = W2[(i+1)*64 + j];
      float w2 = W2[(i+2)*64 + j];
      float w3 = W2[(i+3)*64 + j];
      float4 hv = *(const float4*)&h1s[g*128 + i];
      acc += hv.x*w0 + hv.y*w1 + hv.z*w2 + hv.w*w3;
    }
    h2s[g*64 + j] = fmaxf(acc, 0.f);
  }
  __syncthreads();

  // out = sigmoid(h2 @ W3 + b3)
  if (t < U_*4) {
    const int u = t >> 2, sub = t & 3;
    float a = 0.f;
    #pragma unroll
    for (int i = 0; i < 16; ++i) a += h2s[u*64 + sub*16 + i] * W3[sub*16 + i];
    a += __shfl_xor(a, 1);
    a += __shfl_xor(a, 2);
    if (sub == 0) out[u0 + u] = 1.f / (1.f + __expf(-(a + b3[0])));
  }
}

extern "C" void kernel_launch(void* const* d_in, const int* in_sizes, int n_in,
                              void* d_out, int out_size, void* d_ws, size_t ws_size,
                              hipStream_t stream) {
  const int*   film_hist = (const int*)d_in[0];
  const float* ratings   = (const float*)d_in[1];
  const int*   lengths   = (const int*)d_in[2];
  const int*   film_idx  = (const int*)d_in[3];
  const float* emb       = (const float*)d_in[4];
  const float* W1 = (const float*)d_in[5];
  const float* b1 = (const float*)d_in[6];
  const float* W2 = (const float*)d_in[7];
  const float* b2 = (const float*)d_in[8];
  const float* W3 = (const float*)d_in[9];
  const float* b3 = (const float*)d_in[10];

  float* xbuf = (float*)d_ws;                 // B*320 f32 = 5.24 MB
  float* outp = (float*)d_out;

  stats_kernel<<<B_/4, 256, 0, stream>>>(film_hist, ratings, lengths, film_idx, emb, xbuf);
  mlp_kernel<<<B_/U_, 256, 0, stream>>>(xbuf, W1, b1, W2, b2, W3, b3, outp);
}

// Round 16
// 56.007 us; speedup vs baseline: 1.0849x; 1.0849x over previous
//
#include <hip/hip_runtime.h>
#include <hip/hip_bf16.h>
#include <stdint.h>

// Recommender: B=4096 users, L=200 history, D=64 emb, F=100000 films.
// Kernel A (stats): ONE USER PER 256-THREAD BLOCK, 4 lanes per dim
//   (d = t>>2, sub = t&3; each thread owns keys l = sub+4i, i<ceil((n-sub)/4)
//   <= 50 -> 2 chunks of 32). COMPACT LOOPED CODE (~1.3K inst, all 4 waves on
//   the same path -> I$-resident; the wave-per-user variant was I-fetch bound
//   at 10K straight-line inst). Register planes: 2 x W[16]. Per-bit median
//   counts combined across the dim-quad with v_update_dpp quad_perm adds
//   (VALU-speed, no LDS-pipe shfl chain). Verified math reused verbatim:
//   dual 16x16 XS bit-transpose, plane-space sign fix (plane15=~S, plane_b^=S),
//   alive-mask formula, bucket-midpoint decode (absmax 0 in rounds 5-15).
// Kernel B: tiny MLP 320->128->64->1 + sigmoid, 4 users/block (unchanged).

#define B_ 4096
#define L_ 200
#define D_ 64

__device__ __forceinline__ void xpose_sign(uint32_t (&W)[16]) {
  // dual 16x16 bit-matrix transpose (verified): plane of raw key-bit bb is
  // W[15-bb]; key s (within chunk) at plane bit (15-(s>>1)) + 16*(s&1).
  #define XS(k, jj, m) { uint32_t tt = ((W[k] ^ (W[(k)|(jj)] >> (jj))) & (m)); \
                         W[k] ^= tt; W[(k)|(jj)] ^= (tt << (jj)); }
  XS(0,8,0x00FF00FFu) XS(1,8,0x00FF00FFu) XS(2,8,0x00FF00FFu) XS(3,8,0x00FF00FFu)
  XS(4,8,0x00FF00FFu) XS(5,8,0x00FF00FFu) XS(6,8,0x00FF00FFu) XS(7,8,0x00FF00FFu)
  XS(0,4,0x0F0F0F0Fu) XS(1,4,0x0F0F0F0Fu) XS(2,4,0x0F0F0F0Fu) XS(3,4,0x0F0F0F0Fu)
  XS(8,4,0x0F0F0F0Fu) XS(9,4,0x0F0F0F0Fu) XS(10,4,0x0F0F0F0Fu) XS(11,4,0x0F0F0F0Fu)
  XS(0,2,0x33333333u) XS(1,2,0x33333333u) XS(4,2,0x33333333u) XS(5,2,0x33333333u)
  XS(8,2,0x33333333u) XS(9,2,0x33333333u) XS(12,2,0x33333333u) XS(13,2,0x33333333u)
  XS(0,1,0x55555555u) XS(2,1,0x55555555u) XS(4,1,0x55555555u) XS(6,1,0x55555555u)
  XS(8,1,0x55555555u) XS(10,1,0x55555555u) XS(12,1,0x55555555u) XS(14,1,0x55555555u)
  #undef XS
  // sortable-key transform in plane space: key15 = ~sign; key_b = raw_b ^ sign
  const uint32_t S = W[0];                   // raw bit15 (sign) plane
  W[0] = ~S;
  #pragma unroll
  for (int j = 1; j < 16; ++j) W[j] ^= S;
}

template<bool TWO>
__device__ __forceinline__ uint32_t select_med(
    const uint32_t (&W0)[16], const uint32_t (&W1x)[16],
    uint32_t a0, uint32_t a1, int k)
{
  uint32_t prefix = 0;
  #pragma unroll
  for (int bb = 15; bb >= 0; --bb) {
    const uint32_t z0 = a0 & ~W0[15 - bb];   // zero-side keys, chunk 0
    int cnt = __popc(z0);
    uint32_t z1 = 0u;
    if (TWO) {
      z1 = a1 & ~W1x[15 - bb];
      cnt += __popc(z1);
    }
    // sum across the 4 sub-lanes of this dim: quad_perm xor1 then xor2 (VALU)
    cnt += __builtin_amdgcn_update_dpp(0, cnt, 0xB1, 0xF, 0xF, true); // [1,0,3,2]
    cnt += __builtin_amdgcn_update_dpp(0, cnt, 0x4E, 0xF, 0xF, true); // [2,3,0,1]
    const bool zs = (k < cnt);
    a0 = zs ? z0 : (a0 ^ z0);
    if (TWO) a1 = zs ? z1 : (a1 ^ z1);
    k      = zs ? k : (k - cnt);
    prefix = zs ? prefix : (prefix | (1u << bb));
  }
  return prefix;
}

__global__ __launch_bounds__(256) void stats_kernel(
    const int* __restrict__ film_hist,
    const float* __restrict__ ratings,
    const int* __restrict__ lengths,
    const int* __restrict__ film_indices,
    const float* __restrict__ emb,
    float* __restrict__ x)
{
  __shared__ uint2 pair_s[L_];               // {h<<8, rating bits}
  __shared__ float red[4];
  __shared__ float ue[4*D_];                 // [min|max|mean|med]

  const int t = threadIdx.x;
  const int wv = t >> 6;
  const int lane = t & 63;
  const int d = t >> 2;                      // dim 0..63
  const int sub = t & 3;
  const int b = blockIdx.x;
  const int n = lengths[b];                  // block-uniform

  // film embedding (issued early; written at the end by t<64)
  const int fi = film_indices[b];
  const float fev = (t < 64) ? emb[(size_t)fi * D_ + t] : 0.f;

  // ---- stage {h<<8, rating}; mean-rating partials ----
  float r = 0.f;
  if (t < n) {
    uint2 e;
    e.x = ((uint32_t)film_hist[(size_t)b*L_ + t]) << 8;  // emb byte offset
    const float rv = ratings[(size_t)b*L_ + t];
    e.y = __float_as_uint(rv);
    pair_s[t] = e;
    r = rv;
  }
  float s = r;
  #pragma unroll
  for (int off = 32; off; off >>= 1) s += __shfl_down(s, off);
  if (lane == 0) red[wv] = s;
  __syncthreads();                           // (1) staging + mean partials
  const float mr1 = 0.1f - (red[0]+red[1]+red[2]+red[3]) / (float)n;

  // ---- gather + stats + raw key pack: 13 groups of 4 keys ----
  const char* eb = (const char*)emb;
  const uint32_t d4 = (uint32_t)d * 4u;
  float vmin = __builtin_inff(), vmax = -__builtin_inff(), vsum = 0.f;
  uint32_t W0[16], W1x[16];
  #pragma unroll
  for (int j = 0; j < 16; ++j) { W0[j] = 0u; W1x[j] = 0u; }

  #pragma unroll
  for (int g = 0; g < 13; ++g) {
    if (16*g < n) {                          // block-uniform guard
      uint32_t kk[4];
      #pragma unroll
      for (int j = 0; j < 4; ++j) {
        const int l = sub + 16*g + 4*j;      // key index i = 4g+j
        const int lc = (l < n) ? l : (n - 1);
        const uint2 e = pair_s[lc];          // 4-addr broadcast read
        const float w = *(const float*)(eb + (e.x + d4))
                        * (__uint_as_float(e.y) + mr1);
        vmin = fminf(vmin, (l < n) ? w :  __builtin_inff());
        vmax = fmaxf(vmax, (l < n) ? w : -__builtin_inff());
        vsum += (l < n) ? w : 0.f;
        kk[j] = __float_as_uint(w);          // raw bits; sign fixed in planes
      }
      // pack raw high-16 halves: word = (even key | odd key << 16)
      const uint32_t wA = __builtin_amdgcn_perm(kk[1], kk[0], 0x07060302u);
      const uint32_t wB = __builtin_amdgcn_perm(kk[3], kk[2], 0x07060302u);
      if (g < 8) { W0[2*g]       = wA; W0[2*g + 1]       = wB; }
      else       { W1x[2*(g-8)]  = wA; W1x[2*(g-8) + 1]  = wB; }
    }
  }

  // quad-reduce min/max/sum across the 4 subs (one-time, shfl ok)
  vmin = fminf(vmin, __shfl_xor(vmin, 1));
  vmin = fminf(vmin, __shfl_xor(vmin, 2));
  vmax = fmaxf(vmax, __shfl_xor(vmax, 1));
  vmax = fmaxf(vmax, __shfl_xor(vmax, 2));
  vsum += __shfl_xor(vsum, 1);
  vsum += __shfl_xor(vsum, 2);

  // transpose + sign-fix planes (chunk 1 only if any thread has >32 keys)
  const bool two = (n > 128);                // block-uniform
  xpose_sign(W0);
  if (two) xpose_sign(W1x);

  // alive masks (verified formula; v = valid keys of this thread per chunk)
  const int cth = (n > sub) ? ((n - sub + 3) >> 2) : 0;   // <= 50
  const int v0 = (cth < 32) ? cth : 32;
  const int v1 = cth - v0;
  const int ce0 = (v0 + 1) >> 1, cf0 = v0 >> 1;
  uint32_t a0 = ((1u << ce0) - 1u) << (16 - ce0);
  if (cf0) a0 |= ((1u << cf0) - 1u) << (32 - cf0);
  const int ce1 = (v1 + 1) >> 1, cf1 = v1 >> 1;
  uint32_t a1 = ((1u << ce1) - 1u) << (16 - ce1);
  if (cf1) a1 |= ((1u << cf1) - 1u) << (32 - cf1);
  if (v1 == 0) a1 = 0u;

  // bit-serial popc median select (k-th smallest over the dim's n keys)
  const int k = (n - 1) >> 1;
  const uint32_t prefix = two ? select_med<true >(W0, W1x, a0, a1, k)
                              : select_med<false>(W0, W1x, a0, a1, k);

  if (sub == 0) {
    uint32_t key32 = (prefix << 16) | 0x8000u;           // bucket midpoint
    const float med = (prefix & 0x8000u) ? __uint_as_float(key32 ^ 0x80000000u)
                                         : __uint_as_float(~key32);
    ue[d]       = vmin;
    ue[64 + d]  = vmax;
    ue[128 + d] = vsum / (float)n;
    ue[192 + d] = med;
  }
  __syncthreads();                           // (2) ue complete

  // ---- L2-normalize ue, write x = [ue_norm(256) | fe(64)] ----
  const float vv = ue[t];
  float ss = vv * vv;
  #pragma unroll
  for (int off = 32; off; off >>= 1) ss += __shfl_down(ss, off);
  if (lane == 0) red[wv] = ss;
  __syncthreads();                           // (3) sumsq partials
  const float rn = 1.0f / sqrtf(red[0]+red[1]+red[2]+red[3]);

  float* xb = x + (size_t)b * 320;
  xb[t] = vv * rn;
  if (t < 64) xb[256 + t] = fev;
}

#define U_ 4   // users per MLP block -> 1024 blocks

__global__ __launch_bounds__(256) void mlp_kernel(
    const float* __restrict__ x,
    const float* __restrict__ W1, const float* __restrict__ b1,
    const float* __restrict__ W2, const float* __restrict__ b2,
    const float* __restrict__ W3, const float* __restrict__ b3,
    float* __restrict__ out)
{
  __shared__ float xs[U_*320];
  __shared__ float h1s[U_*128];
  __shared__ float h2s[U_*64];
  const int t = threadIdx.x;
  const int u0 = blockIdx.x * U_;

  for (int i = t; i < U_*80; i += 256)
    ((float4*)xs)[i] = ((const float4*)(x + (size_t)u0*320))[i];
  __syncthreads();

  // h1 = relu(x @ W1 + b1): 4 users x 128 out; thread = (j, 2-user group)
  {
    const int j = t & 127, g = t >> 7;
    const int ub = g*2;
    float acc[2];
    const float bj = b1[j];
    acc[0] = bj; acc[1] = bj;
    for (int i = 0; i < 320; i += 4) {
      float w0 = W1[(i+0)*128 + j];
      float w1 = W1[(i+1)*128 + j];
      float w2 = W1[(i+2)*128 + j];
      float w3 = W1[(i+3)*128 + j];
      #pragma unroll
      for (int q = 0; q < 2; ++q) {
        float4 xv = *(const float4*)&xs[(ub+q)*320 + i];   // LDS broadcast in-wave
        acc[q] += xv.x*w0 + xv.y*w1 + xv.z*w2 + xv.w*w3;
      }
    }
    #pragma unroll
    for (int q = 0; q < 2; ++q) h1s[(ub+q)*128 + j] = fmaxf(acc[q], 0.f);
  }
  __syncthreads();

  // h2 = relu(h1 @ W2 + b2): 4 users x 64 out, 1 user per 64-thread group
  {
    const int j = t & 63, g = t >> 6;
    float acc = b2[j];
    for (int i = 0; i < 128; i += 4) {
      float w0 = W2[(i+0)*64 + j];
      float w1 = W2[(i+1)*64 + j];
      float w2 = W2[(i+2)*64 + j];
      float w3 = W2[(i+3)*64 + j];
      float4 hv = *(const float4*)&h1s[g*128 + i];
      acc += hv.x*w0 + hv.y*w1 + hv.z*w2 + hv.w*w3;
    }
    h2s[g*64 + j] = fmaxf(acc, 0.f);
  }
  __syncthreads();

  // out = sigmoid(h2 @ W3 + b3)
  if (t < U_*4) {
    const int u = t >> 2, sub = t & 3;
    float a = 0.f;
    #pragma unroll
    for (int i = 0; i < 16; ++i) a += h2s[u*64 + sub*16 + i] * W3[sub*16 + i];
    a += __shfl_xor(a, 1);
    a += __shfl_xor(a, 2);
    if (sub == 0) out[u0 + u] = 1.f / (1.f + __expf(-(a + b3[0])));
  }
}

extern "C" void kernel_launch(void* const* d_in, const int* in_sizes, int n_in,
                              void* d_out, int out_size, void* d_ws, size_t ws_size,
                              hipStream_t stream) {
  const int*   film_hist = (const int*)d_in[0];
  const float* ratings   = (const float*)d_in[1];
  const int*   lengths   = (const int*)d_in[2];
  const int*   film_idx  = (const int*)d_in[3];
  const float* emb       = (const float*)d_in[4];
  const float* W1 = (const float*)d_in[5];
  const float* b1 = (const float*)d_in[6];
  const float* W2 = (const float*)d_in[7];
  const float* b2 = (const float*)d_in[8];
  const float* W3 = (const float*)d_in[9];
  const float* b3 = (const float*)d_in[10];

  float* xbuf = (float*)d_ws;                 // B*320 f32 = 5.24 MB
  float* outp = (float*)d_out;

  stats_kernel<<<B_, 256, 0, stream>>>(film_hist, ratings, lengths, film_idx, emb, xbuf);
  mlp_kernel<<<B_/U_, 256, 0, stream>>>(xbuf, W1, b1, W2, b2, W3, b3, outp);
}